// Round 23
// baseline (604.062 us; speedup 1.0000x reference)
//
#include <hip/hip_runtime.h>
#include <hip/hip_bf16.h>
#include <math.h>

#define NB 32
#define LSEQ 2048
#define DIN 64
#define NH 256
#define NN 32
#define NLAY 2
#define NCH 32
#define TCH 64    // LSEQ/NCH
#define NBC (NB*NCH)          // 1024 columns
#define LT 32                 // proj l-tile
#define ML1 350
#define ML2 400
#define MOUT 1024
#define LN_EPS 1e-5f

typedef short short8 __attribute__((ext_vector_type(8)));
typedef short short4v __attribute__((ext_vector_type(4)));
typedef float f32x4 __attribute__((ext_vector_type(4)));

__device__ __forceinline__ float bf2f(ushort u) {
    union { uint i; float f; } v; v.i = ((uint)u) << 16; return v.f;
}
__device__ __forceinline__ ushort f2bf(float f) {
    __hip_bfloat16 h = __float2bfloat16(f);
    return *reinterpret_cast<ushort*>(&h);
}

// ---------------- matrix prep: Lmat, Wc, Vmat + scan coefs (E^64) ----------------
__global__ void s4w_matprep(const float* __restrict__ log_dt,
                            const float* __restrict__ C_re, const float* __restrict__ C_im,
                            const float* __restrict__ log_A_real, const float* __restrict__ A_imag,
                            ushort* __restrict__ Lmat, ushort* __restrict__ Wc,
                            ushort* __restrict__ Vmat,
                            float* __restrict__ pr_, float* __restrict__ pi_) {
    int lh = blockIdx.x;          // layer*NH + h
    int t = threadIdx.x;          // 0..63
    __shared__ float ksh[64];
    float dt = expf(log_dt[lh]);
    if (t < NN) {                 // fused scan-coefficient prep
        int idx = lh * NN + t;
        float ar = -expf(log_A_real[idx]);
        float ai = A_imag[idx];
        double dre = (double)(ar * dt), dim = (double)(ai * dt);
        double exT = exp(dre * (double)TCH);
        double ang = dim * (double)TCH;
        pr_[idx] = (float)(exT * cos(ang));
        pi_[idx] = (float)(exT * sin(ang));
    }
    float kacc = 0.f;
    for (int n = 0; n < NN; n++) {
        int idx = lh * NN + n;
        float ar = -expf(log_A_real[idx]);
        float ai = A_imag[idx];
        float dre = ar * dt, dim = ai * dt;
        float e1 = expf(dre);
        float er1 = e1 * cosf(dim), ei1 = e1 * sinf(dim);
        float den = ar * ar + ai * ai;
        float qr = ((er1 - 1.f) * ar + ei1 * ai) / den;
        float qi = (ei1 * ar - (er1 - 1.f) * ai) / den;
        float cr = C_re[idx], ci = C_im[idx];
        float ctr = 2.f * (cr * qr - ci * qi);
        float cti = 2.f * (cr * qi + ci * qr);
        float ed = expf(dre * (float)t);
        float angd = dim * (float)t;
        float erd = ed * cosf(angd), eid = ed * sinf(angd);
        kacc += ctr * erd - cti * eid;
        float ew = expf(dre * (float)(t + 1));
        float angw = dim * (float)(t + 1);
        float ewr = ew * cosf(angw), ewi = ew * sinf(angw);
        float wr = ctr * ewr - cti * ewi;
        float wi = ctr * ewi + cti * ewr;
        Wc[(size_t)lh * 4096 + t * 64 + 2 * n]     = f2bf(wr);
        Wc[(size_t)lh * 4096 + t * 64 + 2 * n + 1] = f2bf(-wi);
        float ev = expf(dre * (float)(63 - t));
        float angv = dim * (float)(63 - t);
        Vmat[(size_t)lh * 4096 + (2 * n) * 64 + t]     = f2bf(ev * cosf(angv));
        Vmat[(size_t)lh * 4096 + (2 * n + 1) * 64 + t] = f2bf(ev * sinf(angv));
    }
    ksh[t] = kacc;
    __syncthreads();
    for (int j = 0; j < 64; j++)
        Lmat[(size_t)lh * 4096 + t * 64 + j] = (j <= t) ? f2bf(ksh[t - j]) : (ushort)0;
}

// ---------------- weight prep: f32 -> bf16 ----------------
__global__ void s4w_wprep(const float* __restrict__ src, ushort* __restrict__ dst, int n) {
    int idx = blockIdx.x * 256 + threadIdx.x;
    if (idx < n) dst[idx] = f2bf(src[idx]);
}

// ---------------- encoder (MFMA): block=(b,c 64-l chunk) -> r_t h-major ----------------
__global__ void __launch_bounds__(256, 2)
s4w_enc(const float* __restrict__ x, const ushort* __restrict__ wenc,
        const float* __restrict__ bias, ushort* __restrict__ r_t) {
    int b = blockIdx.x, c = blockIdx.y;
    int t = threadIdx.x;
    int wave = t >> 6, lane = t & 63;
    int lm = lane & 15, kg = lane >> 4;
    __shared__ __align__(16) ushort xsb[64][72];    // [l][i]
    __shared__ __align__(16) ushort ysb[256][72];   // [h][l]

#pragma unroll
    for (int p = 0; p < 4; p++) {
        int cid = p * 256 + t;
        int l = cid >> 4, i4 = (cid & 15) * 4;
        float4 v = *(const float4*)(x + ((size_t)(b * LSEQ + c * 64 + l)) * DIN + i4);
        xsb[l][i4]     = f2bf(v.x); xsb[l][i4 + 1] = f2bf(v.y);
        xsb[l][i4 + 2] = f2bf(v.z); xsb[l][i4 + 3] = f2bf(v.w);
    }
    __syncthreads();

    f32x4 acc[4][4];
#pragma unroll
    for (int i = 0; i < 4; i++)
#pragma unroll
        for (int j = 0; j < 4; j++) acc[i][j] = (f32x4){0.f, 0.f, 0.f, 0.f};
#pragma unroll
    for (int ks = 0; ks < 2; ks++) {
        short8 av[4], bv[4];
#pragma unroll
        for (int mf = 0; mf < 4; mf++)
            av[mf] = *(const short8*)(wenc + (size_t)(wave * 64 + mf * 16 + lm) * DIN + ks * 32 + kg * 8);
#pragma unroll
        for (int nf = 0; nf < 4; nf++)
            bv[nf] = *(const short8*)&xsb[nf * 16 + lm][ks * 32 + kg * 8];
#pragma unroll
        for (int mf = 0; mf < 4; mf++)
#pragma unroll
            for (int nf = 0; nf < 4; nf++)
                acc[mf][nf] = __builtin_amdgcn_mfma_f32_16x16x32_bf16(av[mf], bv[nf], acc[mf][nf], 0, 0, 0);
    }
    float bb[4][4];
#pragma unroll
    for (int mf = 0; mf < 4; mf++)
#pragma unroll
        for (int j = 0; j < 4; j++)
            bb[mf][j] = bias[wave * 64 + mf * 16 + kg * 4 + j];
#pragma unroll
    for (int mf = 0; mf < 4; mf++)
#pragma unroll
        for (int nf = 0; nf < 4; nf++)
#pragma unroll
            for (int j = 0; j < 4; j++) {
                int h = wave * 64 + mf * 16 + kg * 4 + j;
                int l = nf * 16 + lm;
                ysb[h][l] = f2bf(acc[mf][nf][j] + bb[mf][j]);
            }
    __syncthreads();
    ushort* rd = r_t + ((size_t)t * NBC + b * NCH + c) * 64;
#pragma unroll
    for (int q = 0; q < 8; q++)
        *(short8*)(rd + q * 8) = *(const short8*)&ysb[t][q * 8];
}

// ---------------- fused conv v2: 2 b's per stage (N=64), 8 b's per block ----------------
__global__ void __launch_bounds__(256, 2)
s4w_conv(const ushort* __restrict__ r_t, ushort* __restrict__ u_t,
         const ushort* __restrict__ Lmat, const ushort* __restrict__ Wc,
         const ushort* __restrict__ Vmat,
         const float* __restrict__ pr_, const float* __restrict__ pi_,
         const float* __restrict__ Dp, int layer) {
    int h = blockIdx.x, bq = blockIdx.y;
    int t = threadIdx.x;
    int wave = t >> 6, lane = t & 63;
    int lm = lane & 15, kg = lane >> 4;

    __shared__ __align__(16) ushort uS[64][72];
    __shared__ __align__(16) ushort lS[64][72];
    __shared__ __align__(16) ushort wS[64][72];
    __shared__ __align__(16) ushort vS[64][72];
    __shared__ __align__(16) float  stS[64][68];
    __shared__ __align__(16) ushort sbS[64][72];
    __shared__ __align__(16) ushort yS[64][72];

    const ushort* Lg = Lmat + (size_t)(layer * NH + h) * 4096;
    const ushort* Wg = Wc   + (size_t)(layer * NH + h) * 4096;
    const ushort* Vg = Vmat + (size_t)(layer * NH + h) * 4096;
#pragma unroll
    for (int p = 0; p < 2; p++) {
        int cid = p * 256 + t;
        int r = cid >> 3, o = (cid & 7) * 8;
        *(short8*)&lS[r][o] = *(const short8*)(Lg + r * 64 + o);
        *(short8*)&wS[r][o] = *(const short8*)(Wg + r * 64 + o);
        *(short8*)&vS[r][o] = *(const short8*)(Vg + r * 64 + o);
    }
    float dp = Dp[layer * NH + h];
    float prv = 0.f, piv = 0.f;
    if (t < 64) {
        int n = t & 31;
        prv = pr_[(size_t)(layer * NH + h) * NN + n];
        piv = pi_[(size_t)(layer * NH + h) * NN + n];
    }

    for (int bi = 0; bi < 4; bi++) {
        int b0 = bq * 8 + bi * 2;
        const ushort* rb = r_t + ((size_t)h * NBC + b0 * NCH) * 64;
        ushort* ub = u_t + ((size_t)h * NBC + b0 * NCH) * 64;
        {
            int r = t >> 2, o = (t & 3) * 16;
            *(short8*)&uS[r][o] = *(const short8*)(rb + r * 64 + o);
            *(short8*)&uS[r][o + 8] = *(const short8*)(rb + r * 64 + o + 8);
        }
        __syncthreads();

        {
            f32x4 acc[4];
#pragma unroll
            for (int i = 0; i < 4; i++) acc[i] = (f32x4){0.f, 0.f, 0.f, 0.f};
#pragma unroll
            for (int ks = 0; ks < 2; ks++) {
                short8 av = *(const short8*)&vS[wave * 16 + lm][ks * 32 + kg * 8];
#pragma unroll
                for (int nt = 0; nt < 4; nt++) {
                    short8 bv = *(const short8*)&uS[nt * 16 + lm][ks * 32 + kg * 8];
                    acc[nt] = __builtin_amdgcn_mfma_f32_16x16x32_bf16(av, bv, acc[nt], 0, 0, 0);
                }
            }
#pragma unroll
            for (int nt = 0; nt < 4; nt++) {
                int c = nt * 16 + lm;
                int comp = wave * 16 + kg * 4;
                *(f32x4*)&stS[c][comp] = acc[nt];
            }
        }
        __syncthreads();

        if (t < 64) {
            int half = t >> 5, n = t & 31;
            float sr = 0.f, si = 0.f;
            int r0 = half * 32;
            for (int c = 0; c < NCH; c++) {
                float er = stS[r0 + c][2 * n], ei = stS[r0 + c][2 * n + 1];
                sbS[r0 + c][2 * n] = f2bf(sr);
                sbS[r0 + c][2 * n + 1] = f2bf(si);
                float nsr = prv * sr - piv * si + er;
                float nsi = prv * si + piv * sr + ei;
                sr = nsr; si = nsi;
            }
        }
        __syncthreads();

        f32x4 acc[4];
#pragma unroll
        for (int i = 0; i < 4; i++) acc[i] = (f32x4){0.f, 0.f, 0.f, 0.f};
#pragma unroll
        for (int ks = 0; ks < 2; ks++) {
            short8 avL = *(const short8*)&lS[wave * 16 + lm][ks * 32 + kg * 8];
            short8 avW = *(const short8*)&wS[wave * 16 + lm][ks * 32 + kg * 8];
#pragma unroll
            for (int nt = 0; nt < 4; nt++) {
                short8 bvU = *(const short8*)&uS[nt * 16 + lm][ks * 32 + kg * 8];
                acc[nt] = __builtin_amdgcn_mfma_f32_16x16x32_bf16(avL, bvU, acc[nt], 0, 0, 0);
                short8 bvS = *(const short8*)&sbS[nt * 16 + lm][ks * 32 + kg * 8];
                acc[nt] = __builtin_amdgcn_mfma_f32_16x16x32_bf16(avW, bvS, acc[nt], 0, 0, 0);
            }
        }
#pragma unroll
        for (int nt = 0; nt < 4; nt++) {
            int c = nt * 16 + lm;
            int j0 = wave * 16 + kg * 4;
            short4v uv = *(const short4v*)&uS[c][j0];
            short4v yo;
#pragma unroll
            for (int jj = 0; jj < 4; jj++) {
                float u = bf2f((ushort)uv[jj]);
                float y = acc[nt][jj] + dp * u;
                float g = 0.5f * y * (1.0f + erff(y * 0.70710678118f));
                yo[jj] = (short)f2bf(g);
            }
            *(short4v*)&yS[c][j0] = yo;
        }
        __syncthreads();
        {
            int r = t >> 2, o = (t & 3) * 16;
            *(short8*)(ub + r * 64 + o) = *(const short8*)&yS[r][o];
            *(short8*)(ub + r * 64 + o + 8) = *(const short8*)&yS[r][o + 8];
        }
        __syncthreads();
    }
}

// ---------------- proj v11: 2 barriers/tile; redundant broadcast LN reduce ----------------
__global__ void __launch_bounds__(512, 2)
s4w_proj_mfma(const ushort* __restrict__ u_t, ushort* __restrict__ r_t,
              const ushort* __restrict__ wbf, const float* __restrict__ ob,
              const float* __restrict__ lnw, const float* __restrict__ lnb,
              float* __restrict__ hl, int last, int layer) {
    int b = blockIdx.x;
    int chunk = blockIdx.y;            // 8 chunks of 256 l
    int t = threadIdx.x;
    int wave = t >> 6, lane = t & 63;
    int lm = lane & 15, kg = lane >> 4;
    int hch = t & 255, lp = t >> 8;

    __shared__ __align__(16) ushort ys[LT][NH + 8];    // 16.9 KB
    __shared__ __align__(16) ushort res[LT][NH + 8];   // 16.9 KB
    __shared__ __align__(16) ushort glu[LT][NH + 8];   // 16.9 KB (bf16 pre-LN values)
    __shared__ float ps[LT][9], pq[LT][9];             // 2.3 KB

    const ushort* wp = wbf + (size_t)layer * 512 * NH;

    short8 av[4][8];
#pragma unroll
    for (int mi = 0; mi < 4; mi++) {
        int o = (mi < 2 ? wave * 32 + mi * 16 : 256 + wave * 32 + (mi - 2) * 16) + lm;
#pragma unroll
        for (int ks = 0; ks < 8; ks++)
            av[mi][ks] = *(const short8*)(wp + (size_t)o * NH + ks * 32 + kg * 8);
    }

    float oba[2][4], obg[2][4];
#pragma unroll
    for (int mi = 0; mi < 2; mi++)
#pragma unroll
        for (int j = 0; j < 4; j++) {
            int o = wave * 32 + mi * 16 + kg * 4 + j;
            oba[mi][j] = ob[layer * 2 * NH + o];
            obg[mi][j] = ob[layer * 2 * NH + NH + o];
        }
    float lw = lnw[layer * NH + hch], lb = lnb[layer * NH + hch];

    short8 pre0, pre1, rpre0, rpre1;
    {
        int l0 = chunk * 256;
        int c = l0 >> 6, j0 = l0 & 63;
        size_t base = ((size_t)hch * NBC + b * NCH + c) * 64 + j0 + lp * 16;
        pre0 = *(const short8*)(u_t + base);
        pre1 = *(const short8*)(u_t + base + 8);
        rpre0 = *(const short8*)(r_t + base);
        rpre1 = *(const short8*)(r_t + base + 8);
    }

    for (int tile = 0; tile < 8; tile++) {
        int l0 = chunk * 256 + tile * LT;
        int c = l0 >> 6, j0 = l0 & 63;
        size_t tbase = ((size_t)hch * NBC + b * NCH + c) * 64 + j0 + lp * 16;

        // stage ys + res
        {
            int li0 = lp * 16;
#pragma unroll
            for (int i = 0; i < 8; i++) {
                ys[li0 + i][hch] = (ushort)pre0[i];
                res[li0 + i][hch] = (ushort)rpre0[i];
            }
#pragma unroll
            for (int i = 0; i < 8; i++) {
                ys[li0 + 8 + i][hch] = (ushort)pre1[i];
                res[li0 + 8 + i][hch] = (ushort)rpre1[i];
            }
        }
        if (tile < 7) {
            int l0n = l0 + LT;
            int cn = l0n >> 6, j0n = l0n & 63;
            size_t nbase = ((size_t)hch * NBC + b * NCH + cn) * 64 + j0n + lp * 16;
            pre0 = *(const short8*)(u_t + nbase);
            pre1 = *(const short8*)(u_t + nbase + 8);
            rpre0 = *(const short8*)(r_t + nbase);
            rpre1 = *(const short8*)(r_t + nbase + 8);
        }
        __syncthreads();   // B1: ys/res staged (orders prior tile's ps/glu reads vs rewrites)

        f32x4 acc[4][2];
#pragma unroll
        for (int i = 0; i < 4; i++)
#pragma unroll
            for (int j = 0; j < 2; j++) acc[i][j] = (f32x4){0.f, 0.f, 0.f, 0.f};

#pragma unroll
        for (int ks = 0; ks < 8; ks++) {
            short8 bv[2];
#pragma unroll
            for (int ni = 0; ni < 2; ni++)
                bv[ni] = *(const short8*)&ys[ni * 16 + lm][ks * 32 + kg * 8];
#pragma unroll
            for (int mi = 0; mi < 4; mi++)
#pragma unroll
                for (int ni = 0; ni < 2; ni++)
                    acc[mi][ni] = __builtin_amdgcn_mfma_f32_16x16x32_bf16(av[mi][ks], bv[ni], acc[mi][ni], 0, 0, 0);
        }

        // GLU + bias + residual -> glu (bf16); LN partials via kg-shuffle
#pragma unroll
        for (int ni = 0; ni < 2; ni++) {
            int l = ni * 16 + lm;
            float s = 0.f, q = 0.f;
#pragma unroll
            for (int mi = 0; mi < 2; mi++) {
                int o = wave * 32 + mi * 16 + kg * 4;
#pragma unroll
                for (int j = 0; j < 4; j++) {
                    float a = acc[mi][ni][j] + oba[mi][j];
                    float g = acc[mi + 2][ni][j] + obg[mi][j];
                    float v = a * (1.0f / (1.0f + expf(-g))) + bf2f(res[l][o + j]);
                    glu[l][o + j] = f2bf(v);
                    s += v; q = fmaf(v, v, q);
                }
            }
            s += __shfl_xor(s, 16, 64); q += __shfl_xor(q, 16, 64);
            s += __shfl_xor(s, 32, 64); q += __shfl_xor(q, 32, 64);
            if (kg == 0) { ps[l][wave] = s; pq[l][wave] = q; }
        }
        __syncthreads();   // B2: glu + partials ready

        // normalize: redundant per-thread reduce via LDS broadcast (no B3)
        short8 o0, o1;
#pragma unroll
        for (int i = 0; i < 16; i++) {
            int l = lp * 16 + i;
            float S = 0.f, Q = 0.f;
#pragma unroll
            for (int w = 0; w < 8; w++) { S += ps[l][w]; Q += pq[l][w]; }
            float m = S * (1.0f / NH);
            float var = Q * (1.0f / NH) - m * m;
            float r = rsqrtf(var + LN_EPS);
            float v = (bf2f(glu[l][hch]) - m) * r * lw + lb;
            if (i < 8) o0[i] = (short)f2bf(v);
            else       o1[i - 8] = (short)f2bf(v);
            if (last && chunk == 7 && tile == 7 && lp == 1 && i == 15)
                hl[(size_t)b * NH + hch] = v;   // l = 2047
        }
        ushort* rd = r_t + tbase;
        *(short8*)rd = o0;
        *(short8*)(rd + 8) = o1;
        // no loop barrier: next tile's B1/B2 order all rewrites vs these reads
    }
}

// ---------------- head MLP: one wave per output element ----------------
__global__ void __launch_bounds__(256, 4)
s4w_mlp_wave(const float* __restrict__ in, size_t in_bstride,
             const float* __restrict__ w, const float* __restrict__ bias,
             float* __restrict__ out, int K, int N, int do_relu) {
    int wid = (blockIdx.x * 256 + threadIdx.x) >> 6;
    int lane = threadIdx.x & 63;
    if (wid >= NB * N) return;
    int b = wid / N, o = wid % N;
    const float* ip = in + (size_t)b * in_bstride;
    const float* wp = w + (size_t)o * K;
    float acc = 0.f;
    for (int k = lane; k < K; k += 64) acc = fmaf(wp[k], ip[k], acc);
#pragma unroll
    for (int off = 32; off > 0; off >>= 1) acc += __shfl_xor(acc, off, 64);
    if (lane == 0) {
        float v = acc + bias[o];
        out[(size_t)b * N + o] = do_relu ? fmaxf(v, 0.f) : v;
    }
}

extern "C" void kernel_launch(void* const* d_in, const int* in_sizes, int n_in,
                              void* d_out, int out_size, void* d_ws, size_t ws_size,
                              hipStream_t stream) {
    const float* x          = (const float*)d_in[0];
    const float* enc_w      = (const float*)d_in[1];
    const float* enc_b      = (const float*)d_in[2];
    const float* log_dt     = (const float*)d_in[3];
    const float* C_re       = (const float*)d_in[4];
    const float* C_im       = (const float*)d_in[5];
    const float* log_A_real = (const float*)d_in[6];
    const float* A_imag     = (const float*)d_in[7];
    const float* Dp         = (const float*)d_in[8];
    const float* out_w      = (const float*)d_in[9];
    const float* out_b      = (const float*)d_in[10];
    const float* ln_w       = (const float*)d_in[11];
    const float* ln_b       = (const float*)d_in[12];
    const float* lin1_w     = (const float*)d_in[13];
    const float* lin1_b     = (const float*)d_in[14];
    const float* lin2_w     = (const float*)d_in[15];
    const float* lin2_b     = (const float*)d_in[16];
    const float* lin3_w     = (const float*)d_in[17];
    const float* lin3_b     = (const float*)d_in[18];
    float* outp = (float*)d_out;

    float* ws = (float*)d_ws;
    size_t off = 0;
    ushort* r_t = (ushort*)(ws + off);   off += (size_t)NB * LSEQ * NH / 2;
    ushort* u_t = (ushort*)(ws + off);   off += (size_t)NB * LSEQ * NH / 2;
    ushort* wbf = (ushort*)(ws + off);   off += (size_t)NLAY * 2 * NH * NH / 2;
    ushort* wenc = (ushort*)(ws + off);  off += (size_t)NH * DIN / 2;
    ushort* Lmat = (ushort*)(ws + off);  off += (size_t)NLAY * NH * 4096 / 2;
    ushort* Wc   = (ushort*)(ws + off);  off += (size_t)NLAY * NH * 4096 / 2;
    ushort* Vmat = (ushort*)(ws + off);  off += (size_t)NLAY * NH * 4096 / 2;
    float* pr_ = ws + off;               off += NLAY * NH * NN;
    float* pi_ = ws + off;               off += NLAY * NH * NN;
    float* hl  = ws + off;               off += NB * NH;
    float* t1  = ws + off;               off += NB * ML1;
    float* t2  = ws + off;               off += NB * ML2;

    s4w_matprep<<<NLAY * NH, 64, 0, stream>>>(
        log_dt, C_re, C_im, log_A_real, A_imag, Lmat, Wc, Vmat, pr_, pi_);
    s4w_wprep<<<(NLAY * 2 * NH * NH + 255) / 256, 256, 0, stream>>>(out_w, wbf, NLAY * 2 * NH * NH);
    s4w_wprep<<<(NH * DIN + 255) / 256, 256, 0, stream>>>(enc_w, wenc, NH * DIN);

    s4w_enc<<<dim3(NB, 32), 256, 0, stream>>>(x, wenc, enc_b, r_t);

    for (int layer = 0; layer < NLAY; layer++) {
        s4w_conv<<<dim3(NH, NB / 8), 256, 0, stream>>>(r_t, u_t, Lmat, Wc, Vmat, pr_, pi_, Dp, layer);
        s4w_proj_mfma<<<dim3(NB, 8), 512, 0, stream>>>(
            u_t, r_t, wbf, out_b, ln_w, ln_b, hl, layer == NLAY - 1 ? 1 : 0, layer);
    }

    s4w_mlp_wave<<<(NB * ML1 + 3) / 4, 256, 0, stream>>>(
        hl, NH, lin1_w, lin1_b, t1, NH, ML1, 1);
    s4w_mlp_wave<<<(NB * ML2 + 3) / 4, 256, 0, stream>>>(
        t1, ML1, lin2_w, lin2_b, t2, ML1, ML2, 1);
    s4w_mlp_wave<<<(NB * MOUT + 3) / 4, 256, 0, stream>>>(
        t2, ML2, lin3_w, lin3_b, outp, ML2, MOUT, 0);
}

// Round 24
// 278.273 us; speedup vs baseline: 2.1708x; 2.1708x over previous
//
#include <hip/hip_runtime.h>
#include <hip/hip_bf16.h>
#include <math.h>

#define NB 32
#define LSEQ 2048
#define DIN 64
#define NH 256
#define NN 32
#define NLAY 2
#define NCH 32
#define TCH 64    // LSEQ/NCH
#define NBC (NB*NCH)          // 1024 columns
#define LT 32                 // proj l-tile
#define ML1 350
#define ML2 400
#define MOUT 1024
#define LN_EPS 1e-5f

typedef short short8 __attribute__((ext_vector_type(8)));
typedef short short4v __attribute__((ext_vector_type(4)));
typedef float f32x4 __attribute__((ext_vector_type(4)));

__device__ __forceinline__ float bf2f(ushort u) {
    union { uint i; float f; } v; v.i = ((uint)u) << 16; return v.f;
}
__device__ __forceinline__ ushort f2bf(float f) {
    __hip_bfloat16 h = __float2bfloat16(f);
    return *reinterpret_cast<ushort*>(&h);
}

// ---------------- matrix prep: Lmat, Wc, Vmat + scan coefs (E^64) ----------------
__global__ void s4w_matprep(const float* __restrict__ log_dt,
                            const float* __restrict__ C_re, const float* __restrict__ C_im,
                            const float* __restrict__ log_A_real, const float* __restrict__ A_imag,
                            ushort* __restrict__ Lmat, ushort* __restrict__ Wc,
                            ushort* __restrict__ Vmat,
                            float* __restrict__ pr_, float* __restrict__ pi_) {
    int lh = blockIdx.x;          // layer*NH + h
    int t = threadIdx.x;          // 0..63
    __shared__ float ksh[64];
    float dt = expf(log_dt[lh]);
    if (t < NN) {                 // fused scan-coefficient prep
        int idx = lh * NN + t;
        float ar = -expf(log_A_real[idx]);
        float ai = A_imag[idx];
        double dre = (double)(ar * dt), dim = (double)(ai * dt);
        double exT = exp(dre * (double)TCH);
        double ang = dim * (double)TCH;
        pr_[idx] = (float)(exT * cos(ang));
        pi_[idx] = (float)(exT * sin(ang));
    }
    float kacc = 0.f;
    for (int n = 0; n < NN; n++) {
        int idx = lh * NN + n;
        float ar = -expf(log_A_real[idx]);
        float ai = A_imag[idx];
        float dre = ar * dt, dim = ai * dt;
        float e1 = expf(dre);
        float er1 = e1 * cosf(dim), ei1 = e1 * sinf(dim);
        float den = ar * ar + ai * ai;
        float qr = ((er1 - 1.f) * ar + ei1 * ai) / den;
        float qi = (ei1 * ar - (er1 - 1.f) * ai) / den;
        float cr = C_re[idx], ci = C_im[idx];
        float ctr = 2.f * (cr * qr - ci * qi);
        float cti = 2.f * (cr * qi + ci * qr);
        float ed = expf(dre * (float)t);
        float angd = dim * (float)t;
        float erd = ed * cosf(angd), eid = ed * sinf(angd);
        kacc += ctr * erd - cti * eid;
        float ew = expf(dre * (float)(t + 1));
        float angw = dim * (float)(t + 1);
        float ewr = ew * cosf(angw), ewi = ew * sinf(angw);
        float wr = ctr * ewr - cti * ewi;
        float wi = ctr * ewi + cti * ewr;
        Wc[(size_t)lh * 4096 + t * 64 + 2 * n]     = f2bf(wr);
        Wc[(size_t)lh * 4096 + t * 64 + 2 * n + 1] = f2bf(-wi);
        float ev = expf(dre * (float)(63 - t));
        float angv = dim * (float)(63 - t);
        Vmat[(size_t)lh * 4096 + (2 * n) * 64 + t]     = f2bf(ev * cosf(angv));
        Vmat[(size_t)lh * 4096 + (2 * n + 1) * 64 + t] = f2bf(ev * sinf(angv));
    }
    ksh[t] = kacc;
    __syncthreads();
    for (int j = 0; j < 64; j++)
        Lmat[(size_t)lh * 4096 + t * 64 + j] = (j <= t) ? f2bf(ksh[t - j]) : (ushort)0;
}

// ---------------- weight prep: f32 -> bf16 ----------------
__global__ void s4w_wprep(const float* __restrict__ src, ushort* __restrict__ dst, int n) {
    int idx = blockIdx.x * 256 + threadIdx.x;
    if (idx < n) dst[idx] = f2bf(src[idx]);
}

// ---------------- encoder (MFMA): block=(b,c 64-l chunk) -> r_t h-major ----------------
__global__ void __launch_bounds__(256, 2)
s4w_enc(const float* __restrict__ x, const ushort* __restrict__ wenc,
        const float* __restrict__ bias, ushort* __restrict__ r_t) {
    int b = blockIdx.x, c = blockIdx.y;
    int t = threadIdx.x;
    int wave = t >> 6, lane = t & 63;
    int lm = lane & 15, kg = lane >> 4;
    __shared__ __align__(16) ushort xsb[64][72];    // [l][i]
    __shared__ __align__(16) ushort ysb[256][72];   // [h][l]

#pragma unroll
    for (int p = 0; p < 4; p++) {
        int cid = p * 256 + t;
        int l = cid >> 4, i4 = (cid & 15) * 4;
        float4 v = *(const float4*)(x + ((size_t)(b * LSEQ + c * 64 + l)) * DIN + i4);
        xsb[l][i4]     = f2bf(v.x); xsb[l][i4 + 1] = f2bf(v.y);
        xsb[l][i4 + 2] = f2bf(v.z); xsb[l][i4 + 3] = f2bf(v.w);
    }
    __syncthreads();

    f32x4 acc[4][4];
#pragma unroll
    for (int i = 0; i < 4; i++)
#pragma unroll
        for (int j = 0; j < 4; j++) acc[i][j] = (f32x4){0.f, 0.f, 0.f, 0.f};
#pragma unroll
    for (int ks = 0; ks < 2; ks++) {
        short8 av[4], bv[4];
#pragma unroll
        for (int mf = 0; mf < 4; mf++)
            av[mf] = *(const short8*)(wenc + (size_t)(wave * 64 + mf * 16 + lm) * DIN + ks * 32 + kg * 8);
#pragma unroll
        for (int nf = 0; nf < 4; nf++)
            bv[nf] = *(const short8*)&xsb[nf * 16 + lm][ks * 32 + kg * 8];
#pragma unroll
        for (int mf = 0; mf < 4; mf++)
#pragma unroll
            for (int nf = 0; nf < 4; nf++)
                acc[mf][nf] = __builtin_amdgcn_mfma_f32_16x16x32_bf16(av[mf], bv[nf], acc[mf][nf], 0, 0, 0);
    }
    float bb[4][4];
#pragma unroll
    for (int mf = 0; mf < 4; mf++)
#pragma unroll
        for (int j = 0; j < 4; j++)
            bb[mf][j] = bias[wave * 64 + mf * 16 + kg * 4 + j];
#pragma unroll
    for (int mf = 0; mf < 4; mf++)
#pragma unroll
        for (int nf = 0; nf < 4; nf++)
#pragma unroll
            for (int j = 0; j < 4; j++) {
                int h = wave * 64 + mf * 16 + kg * 4 + j;
                int l = nf * 16 + lm;
                ysb[h][l] = f2bf(acc[mf][nf][j] + bb[mf][j]);
            }
    __syncthreads();
    ushort* rd = r_t + ((size_t)t * NBC + b * NCH + c) * 64;
#pragma unroll
    for (int q = 0; q < 8; q++)
        *(short8*)(rd + q * 8) = *(const short8*)&ysb[t][q * 8];
}

// ---------------- fused conv v2: 2 b's per stage (N=64), 8 b's per block ----------------
__global__ void __launch_bounds__(256, 2)
s4w_conv(const ushort* __restrict__ r_t, ushort* __restrict__ u_t,
         const ushort* __restrict__ Lmat, const ushort* __restrict__ Wc,
         const ushort* __restrict__ Vmat,
         const float* __restrict__ pr_, const float* __restrict__ pi_,
         const float* __restrict__ Dp, int layer) {
    int h = blockIdx.x, bq = blockIdx.y;
    int t = threadIdx.x;
    int wave = t >> 6, lane = t & 63;
    int lm = lane & 15, kg = lane >> 4;

    __shared__ __align__(16) ushort uS[64][72];
    __shared__ __align__(16) ushort lS[64][72];
    __shared__ __align__(16) ushort wS[64][72];
    __shared__ __align__(16) ushort vS[64][72];
    __shared__ __align__(16) float  stS[64][68];
    __shared__ __align__(16) ushort sbS[64][72];
    __shared__ __align__(16) ushort yS[64][72];

    const ushort* Lg = Lmat + (size_t)(layer * NH + h) * 4096;
    const ushort* Wg = Wc   + (size_t)(layer * NH + h) * 4096;
    const ushort* Vg = Vmat + (size_t)(layer * NH + h) * 4096;
#pragma unroll
    for (int p = 0; p < 2; p++) {
        int cid = p * 256 + t;
        int r = cid >> 3, o = (cid & 7) * 8;
        *(short8*)&lS[r][o] = *(const short8*)(Lg + r * 64 + o);
        *(short8*)&wS[r][o] = *(const short8*)(Wg + r * 64 + o);
        *(short8*)&vS[r][o] = *(const short8*)(Vg + r * 64 + o);
    }
    float dp = Dp[layer * NH + h];
    float prv = 0.f, piv = 0.f;
    if (t < 64) {
        int n = t & 31;
        prv = pr_[(size_t)(layer * NH + h) * NN + n];
        piv = pi_[(size_t)(layer * NH + h) * NN + n];
    }

    for (int bi = 0; bi < 4; bi++) {
        int b0 = bq * 8 + bi * 2;
        const ushort* rb = r_t + ((size_t)h * NBC + b0 * NCH) * 64;
        ushort* ub = u_t + ((size_t)h * NBC + b0 * NCH) * 64;
        {
            int r = t >> 2, o = (t & 3) * 16;
            *(short8*)&uS[r][o] = *(const short8*)(rb + r * 64 + o);
            *(short8*)&uS[r][o + 8] = *(const short8*)(rb + r * 64 + o + 8);
        }
        __syncthreads();

        {
            f32x4 acc[4];
#pragma unroll
            for (int i = 0; i < 4; i++) acc[i] = (f32x4){0.f, 0.f, 0.f, 0.f};
#pragma unroll
            for (int ks = 0; ks < 2; ks++) {
                short8 av = *(const short8*)&vS[wave * 16 + lm][ks * 32 + kg * 8];
#pragma unroll
                for (int nt = 0; nt < 4; nt++) {
                    short8 bv = *(const short8*)&uS[nt * 16 + lm][ks * 32 + kg * 8];
                    acc[nt] = __builtin_amdgcn_mfma_f32_16x16x32_bf16(av, bv, acc[nt], 0, 0, 0);
                }
            }
#pragma unroll
            for (int nt = 0; nt < 4; nt++) {
                int c = nt * 16 + lm;
                int comp = wave * 16 + kg * 4;
                *(f32x4*)&stS[c][comp] = acc[nt];
            }
        }
        __syncthreads();

        if (t < 64) {
            int half = t >> 5, n = t & 31;
            float sr = 0.f, si = 0.f;
            int r0 = half * 32;
            for (int c = 0; c < NCH; c++) {
                float er = stS[r0 + c][2 * n], ei = stS[r0 + c][2 * n + 1];
                sbS[r0 + c][2 * n] = f2bf(sr);
                sbS[r0 + c][2 * n + 1] = f2bf(si);
                float nsr = prv * sr - piv * si + er;
                float nsi = prv * si + piv * sr + ei;
                sr = nsr; si = nsi;
            }
        }
        __syncthreads();

        f32x4 acc[4];
#pragma unroll
        for (int i = 0; i < 4; i++) acc[i] = (f32x4){0.f, 0.f, 0.f, 0.f};
#pragma unroll
        for (int ks = 0; ks < 2; ks++) {
            short8 avL = *(const short8*)&lS[wave * 16 + lm][ks * 32 + kg * 8];
            short8 avW = *(const short8*)&wS[wave * 16 + lm][ks * 32 + kg * 8];
#pragma unroll
            for (int nt = 0; nt < 4; nt++) {
                short8 bvU = *(const short8*)&uS[nt * 16 + lm][ks * 32 + kg * 8];
                acc[nt] = __builtin_amdgcn_mfma_f32_16x16x32_bf16(avL, bvU, acc[nt], 0, 0, 0);
                short8 bvS = *(const short8*)&sbS[nt * 16 + lm][ks * 32 + kg * 8];
                acc[nt] = __builtin_amdgcn_mfma_f32_16x16x32_bf16(avW, bvS, acc[nt], 0, 0, 0);
            }
        }
#pragma unroll
        for (int nt = 0; nt < 4; nt++) {
            int c = nt * 16 + lm;
            int j0 = wave * 16 + kg * 4;
            short4v uv = *(const short4v*)&uS[c][j0];
            short4v yo;
#pragma unroll
            for (int jj = 0; jj < 4; jj++) {
                float u = bf2f((ushort)uv[jj]);
                float y = acc[nt][jj] + dp * u;
                float g = 0.5f * y * (1.0f + erff(y * 0.70710678118f));
                yo[jj] = (short)f2bf(g);
            }
            *(short4v*)&yS[c][j0] = yo;
        }
        __syncthreads();
        {
            int r = t >> 2, o = (t & 3) * 16;
            *(short8*)(ub + r * 64 + o) = *(const short8*)&yS[r][o];
            *(short8*)(ub + r * 64 + o + 8) = *(const short8*)&yS[r][o + 8];
        }
        __syncthreads();
    }
}

// ---------------- proj v10: 3 barriers/tile, bf16 glu, shuffle LN partials ----------------
__global__ void __launch_bounds__(512, 2)
s4w_proj_mfma(const ushort* __restrict__ u_t, ushort* __restrict__ r_t,
              const ushort* __restrict__ wbf, const float* __restrict__ ob,
              const float* __restrict__ lnw, const float* __restrict__ lnb,
              float* __restrict__ hl, int last, int layer) {
    int b = blockIdx.x;
    int chunk = blockIdx.y;            // 8 chunks of 256 l
    int t = threadIdx.x;
    int wave = t >> 6, lane = t & 63;
    int lm = lane & 15, kg = lane >> 4;
    int hch = t & 255, lp = t >> 8;

    __shared__ __align__(16) ushort ys[LT][NH + 8];    // 16.9 KB
    __shared__ __align__(16) ushort res[LT][NH + 8];   // 16.9 KB
    __shared__ __align__(16) ushort glu[LT][NH + 8];   // 16.9 KB (bf16 pre-LN values)
    __shared__ float ps[LT][9], pq[LT][9];             // 2.3 KB
    __shared__ float mean_s[LT], rstd_s[LT];

    const ushort* wp = wbf + (size_t)layer * 512 * NH;

    short8 av[4][8];
#pragma unroll
    for (int mi = 0; mi < 4; mi++) {
        int o = (mi < 2 ? wave * 32 + mi * 16 : 256 + wave * 32 + (mi - 2) * 16) + lm;
#pragma unroll
        for (int ks = 0; ks < 8; ks++)
            av[mi][ks] = *(const short8*)(wp + (size_t)o * NH + ks * 32 + kg * 8);
    }

    float oba[2][4], obg[2][4];
#pragma unroll
    for (int mi = 0; mi < 2; mi++)
#pragma unroll
        for (int j = 0; j < 4; j++) {
            int o = wave * 32 + mi * 16 + kg * 4 + j;
            oba[mi][j] = ob[layer * 2 * NH + o];
            obg[mi][j] = ob[layer * 2 * NH + NH + o];
        }
    float lw = lnw[layer * NH + hch], lb = lnb[layer * NH + hch];

    short8 pre0, pre1, rpre0, rpre1;
    {
        int l0 = chunk * 256;
        int c = l0 >> 6, j0 = l0 & 63;
        size_t base = ((size_t)hch * NBC + b * NCH + c) * 64 + j0 + lp * 16;
        pre0 = *(const short8*)(u_t + base);
        pre1 = *(const short8*)(u_t + base + 8);
        rpre0 = *(const short8*)(r_t + base);
        rpre1 = *(const short8*)(r_t + base + 8);
    }

    for (int tile = 0; tile < 8; tile++) {
        int l0 = chunk * 256 + tile * LT;
        int c = l0 >> 6, j0 = l0 & 63;
        size_t tbase = ((size_t)hch * NBC + b * NCH + c) * 64 + j0 + lp * 16;

        // stage ys + res
        {
            int li0 = lp * 16;
#pragma unroll
            for (int i = 0; i < 8; i++) {
                ys[li0 + i][hch] = (ushort)pre0[i];
                res[li0 + i][hch] = (ushort)rpre0[i];
            }
#pragma unroll
            for (int i = 0; i < 8; i++) {
                ys[li0 + 8 + i][hch] = (ushort)pre1[i];
                res[li0 + 8 + i][hch] = (ushort)rpre1[i];
            }
        }
        if (tile < 7) {
            int l0n = l0 + LT;
            int cn = l0n >> 6, j0n = l0n & 63;
            size_t nbase = ((size_t)hch * NBC + b * NCH + cn) * 64 + j0n + lp * 16;
            pre0 = *(const short8*)(u_t + nbase);
            pre1 = *(const short8*)(u_t + nbase + 8);
            rpre0 = *(const short8*)(r_t + nbase);
            rpre1 = *(const short8*)(r_t + nbase + 8);
        }
        __syncthreads();   // B1: ys/res staged (orders vs prior tile's norm reads of glu/mean)

        f32x4 acc[4][2];
#pragma unroll
        for (int i = 0; i < 4; i++)
#pragma unroll
            for (int j = 0; j < 2; j++) acc[i][j] = (f32x4){0.f, 0.f, 0.f, 0.f};

#pragma unroll
        for (int ks = 0; ks < 8; ks++) {
            short8 bv[2];
#pragma unroll
            for (int ni = 0; ni < 2; ni++)
                bv[ni] = *(const short8*)&ys[ni * 16 + lm][ks * 32 + kg * 8];
#pragma unroll
            for (int mi = 0; mi < 4; mi++)
#pragma unroll
                for (int ni = 0; ni < 2; ni++)
                    acc[mi][ni] = __builtin_amdgcn_mfma_f32_16x16x32_bf16(av[mi][ks], bv[ni], acc[mi][ni], 0, 0, 0);
        }

        // GLU + bias + residual -> glu (bf16); LN partials via kg-shuffle
#pragma unroll
        for (int ni = 0; ni < 2; ni++) {
            int l = ni * 16 + lm;
            float s = 0.f, q = 0.f;
#pragma unroll
            for (int mi = 0; mi < 2; mi++) {
                int o = wave * 32 + mi * 16 + kg * 4;
#pragma unroll
                for (int j = 0; j < 4; j++) {
                    float a = acc[mi][ni][j] + oba[mi][j];
                    float g = acc[mi + 2][ni][j] + obg[mi][j];
                    float v = a * (1.0f / (1.0f + expf(-g))) + bf2f(res[l][o + j]);
                    glu[l][o + j] = f2bf(v);
                    s += v; q = fmaf(v, v, q);
                }
            }
            s += __shfl_xor(s, 16, 64); q += __shfl_xor(q, 16, 64);
            s += __shfl_xor(s, 32, 64); q += __shfl_xor(q, 32, 64);
            if (kg == 0) { ps[l][wave] = s; pq[l][wave] = q; }
        }
        __syncthreads();   // B2: glu + partials ready

        if (t < LT) {
            float S = 0.f, Q = 0.f;
#pragma unroll
            for (int w = 0; w < 8; w++) { S += ps[t][w]; Q += pq[t][w]; }
            float m = S * (1.0f / NH);
            float v = Q * (1.0f / NH) - m * m;
            mean_s[t] = m; rstd_s[t] = rsqrtf(v + LN_EPS);
        }
        __syncthreads();   // B3: mean/rstd ready

        short8 o0, o1;
#pragma unroll
        for (int lq = 0; lq < 8; lq++) {
            int l = lp * 16 + lq;
            float v = (bf2f(glu[l][hch]) - mean_s[l]) * rstd_s[l] * lw + lb;
            o0[lq] = (short)f2bf(v);
        }
#pragma unroll
        for (int lq = 0; lq < 8; lq++) {
            int l = lp * 16 + 8 + lq;
            float v = (bf2f(glu[l][hch]) - mean_s[l]) * rstd_s[l] * lw + lb;
            o1[lq] = (short)f2bf(v);
            if (last && chunk == 7 && tile == 7 && lp == 1 && lq == 7)
                hl[(size_t)b * NH + hch] = v;   // l = 2047
        }
        ushort* rd = r_t + tbase;
        *(short8*)rd = o0;
        *(short8*)(rd + 8) = o1;
        // no loop barrier: next tile's B1 orders glu/mean rewrites vs these reads
    }
}

// ---------------- head MLP: one wave per output element ----------------
__global__ void __launch_bounds__(256, 4)
s4w_mlp_wave(const float* __restrict__ in, size_t in_bstride,
             const float* __restrict__ w, const float* __restrict__ bias,
             float* __restrict__ out, int K, int N, int do_relu) {
    int wid = (blockIdx.x * 256 + threadIdx.x) >> 6;
    int lane = threadIdx.x & 63;
    if (wid >= NB * N) return;
    int b = wid / N, o = wid % N;
    const float* ip = in + (size_t)b * in_bstride;
    const float* wp = w + (size_t)o * K;
    float acc = 0.f;
    for (int k = lane; k < K; k += 64) acc = fmaf(wp[k], ip[k], acc);
#pragma unroll
    for (int off = 32; off > 0; off >>= 1) acc += __shfl_xor(acc, off, 64);
    if (lane == 0) {
        float v = acc + bias[o];
        out[(size_t)b * N + o] = do_relu ? fmaxf(v, 0.f) : v;
    }
}

extern "C" void kernel_launch(void* const* d_in, const int* in_sizes, int n_in,
                              void* d_out, int out_size, void* d_ws, size_t ws_size,
                              hipStream_t stream) {
    const float* x          = (const float*)d_in[0];
    const float* enc_w      = (const float*)d_in[1];
    const float* enc_b      = (const float*)d_in[2];
    const float* log_dt     = (const float*)d_in[3];
    const float* C_re       = (const float*)d_in[4];
    const float* C_im       = (const float*)d_in[5];
    const float* log_A_real = (const float*)d_in[6];
    const float* A_imag     = (const float*)d_in[7];
    const float* Dp         = (const float*)d_in[8];
    const float* out_w      = (const float*)d_in[9];
    const float* out_b      = (const float*)d_in[10];
    const float* ln_w       = (const float*)d_in[11];
    const float* ln_b       = (const float*)d_in[12];
    const float* lin1_w     = (const float*)d_in[13];
    const float* lin1_b     = (const float*)d_in[14];
    const float* lin2_w     = (const float*)d_in[15];
    const float* lin2_b     = (const float*)d_in[16];
    const float* lin3_w     = (const float*)d_in[17];
    const float* lin3_b     = (const float*)d_in[18];
    float* outp = (float*)d_out;

    float* ws = (float*)d_ws;
    size_t off = 0;
    ushort* r_t = (ushort*)(ws + off);   off += (size_t)NB * LSEQ * NH / 2;
    ushort* u_t = (ushort*)(ws + off);   off += (size_t)NB * LSEQ * NH / 2;
    ushort* wbf = (ushort*)(ws + off);   off += (size_t)NLAY * 2 * NH * NH / 2;
    ushort* wenc = (ushort*)(ws + off);  off += (size_t)NH * DIN / 2;
    ushort* Lmat = (ushort*)(ws + off);  off += (size_t)NLAY * NH * 4096 / 2;
    ushort* Wc   = (ushort*)(ws + off);  off += (size_t)NLAY * NH * 4096 / 2;
    ushort* Vmat = (ushort*)(ws + off);  off += (size_t)NLAY * NH * 4096 / 2;
    float* pr_ = ws + off;               off += NLAY * NH * NN;
    float* pi_ = ws + off;               off += NLAY * NH * NN;
    float* hl  = ws + off;               off += NB * NH;
    float* t1  = ws + off;               off += NB * ML1;
    float* t2  = ws + off;               off += NB * ML2;

    s4w_matprep<<<NLAY * NH, 64, 0, stream>>>(
        log_dt, C_re, C_im, log_A_real, A_imag, Lmat, Wc, Vmat, pr_, pi_);
    s4w_wprep<<<(NLAY * 2 * NH * NH + 255) / 256, 256, 0, stream>>>(out_w, wbf, NLAY * 2 * NH * NH);
    s4w_wprep<<<(NH * DIN + 255) / 256, 256, 0, stream>>>(enc_w, wenc, NH * DIN);

    s4w_enc<<<dim3(NB, 32), 256, 0, stream>>>(x, wenc, enc_b, r_t);

    for (int layer = 0; layer < NLAY; layer++) {
        s4w_conv<<<dim3(NH, NB / 8), 256, 0, stream>>>(r_t, u_t, Lmat, Wc, Vmat, pr_, pi_, Dp, layer);
        s4w_proj_mfma<<<dim3(NB, 8), 512, 0, stream>>>(
            u_t, r_t, wbf, out_b, ln_w, ln_b, hl, layer == NLAY - 1 ? 1 : 0, layer);
    }

    s4w_mlp_wave<<<(NB * ML1 + 3) / 4, 256, 0, stream>>>(
        hl, NH, lin1_w, lin1_b, t1, NH, ML1, 1);
    s4w_mlp_wave<<<(NB * ML2 + 3) / 4, 256, 0, stream>>>(
        t1, ML1, lin2_w, lin2_b, t2, ML1, ML2, 1);
    s4w_mlp_wave<<<(NB * MOUT + 3) / 4, 256, 0, stream>>>(
        t2, ML2, lin3_w, lin3_b, outp, ML2, MOUT, 0);
}

// Round 25
// 277.817 us; speedup vs baseline: 2.1743x; 1.0016x over previous
//
#include <hip/hip_runtime.h>
#include <hip/hip_bf16.h>
#include <math.h>

#define NB 32
#define LSEQ 2048
#define DIN 64
#define NH 256
#define NN 32
#define NLAY 2
#define NCH 32
#define TCH 64    // LSEQ/NCH
#define NBC (NB*NCH)          // 1024 columns
#define LT 32                 // proj l-tile
#define ML1 350
#define ML2 400
#define MOUT 1024
#define LN_EPS 1e-5f

typedef short short8 __attribute__((ext_vector_type(8)));
typedef short short4v __attribute__((ext_vector_type(4)));
typedef float f32x4 __attribute__((ext_vector_type(4)));

__device__ __forceinline__ float bf2f(ushort u) {
    union { uint i; float f; } v; v.i = ((uint)u) << 16; return v.f;
}
__device__ __forceinline__ ushort f2bf(float f) {
    __hip_bfloat16 h = __float2bfloat16(f);
    return *reinterpret_cast<ushort*>(&h);
}

// ---------------- matrix prep: Lmat, Wc, Vmat + scan coefs (E^64) ----------------
__global__ void s4w_matprep(const float* __restrict__ log_dt,
                            const float* __restrict__ C_re, const float* __restrict__ C_im,
                            const float* __restrict__ log_A_real, const float* __restrict__ A_imag,
                            ushort* __restrict__ Lmat, ushort* __restrict__ Wc,
                            ushort* __restrict__ Vmat,
                            float* __restrict__ pr_, float* __restrict__ pi_) {
    int lh = blockIdx.x;          // layer*NH + h
    int t = threadIdx.x;          // 0..63
    __shared__ float ksh[64];
    float dt = expf(log_dt[lh]);
    if (t < NN) {                 // fused scan-coefficient prep
        int idx = lh * NN + t;
        float ar = -expf(log_A_real[idx]);
        float ai = A_imag[idx];
        double dre = (double)(ar * dt), dim = (double)(ai * dt);
        double exT = exp(dre * (double)TCH);
        double ang = dim * (double)TCH;
        pr_[idx] = (float)(exT * cos(ang));
        pi_[idx] = (float)(exT * sin(ang));
    }
    float kacc = 0.f;
    for (int n = 0; n < NN; n++) {
        int idx = lh * NN + n;
        float ar = -expf(log_A_real[idx]);
        float ai = A_imag[idx];
        float dre = ar * dt, dim = ai * dt;
        float e1 = expf(dre);
        float er1 = e1 * cosf(dim), ei1 = e1 * sinf(dim);
        float den = ar * ar + ai * ai;
        float qr = ((er1 - 1.f) * ar + ei1 * ai) / den;
        float qi = (ei1 * ar - (er1 - 1.f) * ai) / den;
        float cr = C_re[idx], ci = C_im[idx];
        float ctr = 2.f * (cr * qr - ci * qi);
        float cti = 2.f * (cr * qi + ci * qr);
        float ed = expf(dre * (float)t);
        float angd = dim * (float)t;
        float erd = ed * cosf(angd), eid = ed * sinf(angd);
        kacc += ctr * erd - cti * eid;
        float ew = expf(dre * (float)(t + 1));
        float angw = dim * (float)(t + 1);
        float ewr = ew * cosf(angw), ewi = ew * sinf(angw);
        float wr = ctr * ewr - cti * ewi;
        float wi = ctr * ewi + cti * ewr;
        Wc[(size_t)lh * 4096 + t * 64 + 2 * n]     = f2bf(wr);
        Wc[(size_t)lh * 4096 + t * 64 + 2 * n + 1] = f2bf(-wi);
        float ev = expf(dre * (float)(63 - t));
        float angv = dim * (float)(63 - t);
        Vmat[(size_t)lh * 4096 + (2 * n) * 64 + t]     = f2bf(ev * cosf(angv));
        Vmat[(size_t)lh * 4096 + (2 * n + 1) * 64 + t] = f2bf(ev * sinf(angv));
    }
    ksh[t] = kacc;
    __syncthreads();
    for (int j = 0; j < 64; j++)
        Lmat[(size_t)lh * 4096 + t * 64 + j] = (j <= t) ? f2bf(ksh[t - j]) : (ushort)0;
}

// ---------------- weight prep: f32 -> bf16 ----------------
__global__ void s4w_wprep(const float* __restrict__ src, ushort* __restrict__ dst, int n) {
    int idx = blockIdx.x * 256 + threadIdx.x;
    if (idx < n) dst[idx] = f2bf(src[idx]);
}

// ---------------- encoder (MFMA): block=(b,c 64-l chunk) -> r_t h-major ----------------
__global__ void __launch_bounds__(256, 2)
s4w_enc(const float* __restrict__ x, const ushort* __restrict__ wenc,
        const float* __restrict__ bias, ushort* __restrict__ r_t) {
    int b = blockIdx.x, c = blockIdx.y;
    int t = threadIdx.x;
    int wave = t >> 6, lane = t & 63;
    int lm = lane & 15, kg = lane >> 4;
    __shared__ __align__(16) ushort xsb[64][72];    // [l][i]
    __shared__ __align__(16) ushort ysb[256][72];   // [h][l]

#pragma unroll
    for (int p = 0; p < 4; p++) {
        int cid = p * 256 + t;
        int l = cid >> 4, i4 = (cid & 15) * 4;
        float4 v = *(const float4*)(x + ((size_t)(b * LSEQ + c * 64 + l)) * DIN + i4);
        xsb[l][i4]     = f2bf(v.x); xsb[l][i4 + 1] = f2bf(v.y);
        xsb[l][i4 + 2] = f2bf(v.z); xsb[l][i4 + 3] = f2bf(v.w);
    }
    __syncthreads();

    f32x4 acc[4][4];
#pragma unroll
    for (int i = 0; i < 4; i++)
#pragma unroll
        for (int j = 0; j < 4; j++) acc[i][j] = (f32x4){0.f, 0.f, 0.f, 0.f};
#pragma unroll
    for (int ks = 0; ks < 2; ks++) {
        short8 av[4], bv[4];
#pragma unroll
        for (int mf = 0; mf < 4; mf++)
            av[mf] = *(const short8*)(wenc + (size_t)(wave * 64 + mf * 16 + lm) * DIN + ks * 32 + kg * 8);
#pragma unroll
        for (int nf = 0; nf < 4; nf++)
            bv[nf] = *(const short8*)&xsb[nf * 16 + lm][ks * 32 + kg * 8];
#pragma unroll
        for (int mf = 0; mf < 4; mf++)
#pragma unroll
            for (int nf = 0; nf < 4; nf++)
                acc[mf][nf] = __builtin_amdgcn_mfma_f32_16x16x32_bf16(av[mf], bv[nf], acc[mf][nf], 0, 0, 0);
    }
    float bb[4][4];
#pragma unroll
    for (int mf = 0; mf < 4; mf++)
#pragma unroll
        for (int j = 0; j < 4; j++)
            bb[mf][j] = bias[wave * 64 + mf * 16 + kg * 4 + j];
#pragma unroll
    for (int mf = 0; mf < 4; mf++)
#pragma unroll
        for (int nf = 0; nf < 4; nf++)
#pragma unroll
            for (int j = 0; j < 4; j++) {
                int h = wave * 64 + mf * 16 + kg * 4 + j;
                int l = nf * 16 + lm;
                ysb[h][l] = f2bf(acc[mf][nf][j] + bb[mf][j]);
            }
    __syncthreads();
    ushort* rd = r_t + ((size_t)t * NBC + b * NCH + c) * 64;
#pragma unroll
    for (int q = 0; q < 8; q++)
        *(short8*)(rd + q * 8) = *(const short8*)&ysb[t][q * 8];
}

// ---------------- fused conv v2: 2 b's per stage (N=64), 8 b's per block ----------------
__global__ void __launch_bounds__(256, 2)
s4w_conv(const ushort* __restrict__ r_t, ushort* __restrict__ u_t,
         const ushort* __restrict__ Lmat, const ushort* __restrict__ Wc,
         const ushort* __restrict__ Vmat,
         const float* __restrict__ pr_, const float* __restrict__ pi_,
         const float* __restrict__ Dp, int layer) {
    int h = blockIdx.x, bq = blockIdx.y;
    int t = threadIdx.x;
    int wave = t >> 6, lane = t & 63;
    int lm = lane & 15, kg = lane >> 4;

    __shared__ __align__(16) ushort uS[64][72];
    __shared__ __align__(16) ushort lS[64][72];
    __shared__ __align__(16) ushort wS[64][72];
    __shared__ __align__(16) ushort vS[64][72];
    __shared__ __align__(16) float  stS[64][68];
    __shared__ __align__(16) ushort sbS[64][72];
    __shared__ __align__(16) ushort yS[64][72];

    const ushort* Lg = Lmat + (size_t)(layer * NH + h) * 4096;
    const ushort* Wg = Wc   + (size_t)(layer * NH + h) * 4096;
    const ushort* Vg = Vmat + (size_t)(layer * NH + h) * 4096;
#pragma unroll
    for (int p = 0; p < 2; p++) {
        int cid = p * 256 + t;
        int r = cid >> 3, o = (cid & 7) * 8;
        *(short8*)&lS[r][o] = *(const short8*)(Lg + r * 64 + o);
        *(short8*)&wS[r][o] = *(const short8*)(Wg + r * 64 + o);
        *(short8*)&vS[r][o] = *(const short8*)(Vg + r * 64 + o);
    }
    float dp = Dp[layer * NH + h];
    float prv = 0.f, piv = 0.f;
    if (t < 64) {
        int n = t & 31;
        prv = pr_[(size_t)(layer * NH + h) * NN + n];
        piv = pi_[(size_t)(layer * NH + h) * NN + n];
    }

    for (int bi = 0; bi < 4; bi++) {
        int b0 = bq * 8 + bi * 2;
        const ushort* rb = r_t + ((size_t)h * NBC + b0 * NCH) * 64;
        ushort* ub = u_t + ((size_t)h * NBC + b0 * NCH) * 64;
        {
            int r = t >> 2, o = (t & 3) * 16;
            *(short8*)&uS[r][o] = *(const short8*)(rb + r * 64 + o);
            *(short8*)&uS[r][o + 8] = *(const short8*)(rb + r * 64 + o + 8);
        }
        __syncthreads();

        {
            f32x4 acc[4];
#pragma unroll
            for (int i = 0; i < 4; i++) acc[i] = (f32x4){0.f, 0.f, 0.f, 0.f};
#pragma unroll
            for (int ks = 0; ks < 2; ks++) {
                short8 av = *(const short8*)&vS[wave * 16 + lm][ks * 32 + kg * 8];
#pragma unroll
                for (int nt = 0; nt < 4; nt++) {
                    short8 bv = *(const short8*)&uS[nt * 16 + lm][ks * 32 + kg * 8];
                    acc[nt] = __builtin_amdgcn_mfma_f32_16x16x32_bf16(av, bv, acc[nt], 0, 0, 0);
                }
            }
#pragma unroll
            for (int nt = 0; nt < 4; nt++) {
                int c = nt * 16 + lm;
                int comp = wave * 16 + kg * 4;
                *(f32x4*)&stS[c][comp] = acc[nt];
            }
        }
        __syncthreads();

        if (t < 64) {
            int half = t >> 5, n = t & 31;
            float sr = 0.f, si = 0.f;
            int r0 = half * 32;
            for (int c = 0; c < NCH; c++) {
                float er = stS[r0 + c][2 * n], ei = stS[r0 + c][2 * n + 1];
                sbS[r0 + c][2 * n] = f2bf(sr);
                sbS[r0 + c][2 * n + 1] = f2bf(si);
                float nsr = prv * sr - piv * si + er;
                float nsi = prv * si + piv * sr + ei;
                sr = nsr; si = nsi;
            }
        }
        __syncthreads();

        f32x4 acc[4];
#pragma unroll
        for (int i = 0; i < 4; i++) acc[i] = (f32x4){0.f, 0.f, 0.f, 0.f};
#pragma unroll
        for (int ks = 0; ks < 2; ks++) {
            short8 avL = *(const short8*)&lS[wave * 16 + lm][ks * 32 + kg * 8];
            short8 avW = *(const short8*)&wS[wave * 16 + lm][ks * 32 + kg * 8];
#pragma unroll
            for (int nt = 0; nt < 4; nt++) {
                short8 bvU = *(const short8*)&uS[nt * 16 + lm][ks * 32 + kg * 8];
                acc[nt] = __builtin_amdgcn_mfma_f32_16x16x32_bf16(avL, bvU, acc[nt], 0, 0, 0);
                short8 bvS = *(const short8*)&sbS[nt * 16 + lm][ks * 32 + kg * 8];
                acc[nt] = __builtin_amdgcn_mfma_f32_16x16x32_bf16(avW, bvS, acc[nt], 0, 0, 0);
            }
        }
#pragma unroll
        for (int nt = 0; nt < 4; nt++) {
            int c = nt * 16 + lm;
            int j0 = wave * 16 + kg * 4;
            short4v uv = *(const short4v*)&uS[c][j0];
            short4v yo;
#pragma unroll
            for (int jj = 0; jj < 4; jj++) {
                float u = bf2f((ushort)uv[jj]);
                float y = acc[nt][jj] + dp * u;
                float g = 0.5f * y * (1.0f + erff(y * 0.70710678118f));
                yo[jj] = (short)f2bf(g);
            }
            *(short4v*)&yS[c][j0] = yo;
        }
        __syncthreads();
        {
            int r = t >> 2, o = (t & 3) * 16;
            *(short8*)(ub + r * 64 + o) = *(const short8*)&yS[r][o];
            *(short8*)(ub + r * 64 + o + 8) = *(const short8*)&yS[r][o + 8];
        }
        __syncthreads();
    }
}

// ---------------- proj v12: v10 + res stored non-transposed [h][l] (2 vec writes) ----------------
__global__ void __launch_bounds__(512, 2)
s4w_proj_mfma(const ushort* __restrict__ u_t, ushort* __restrict__ r_t,
              const ushort* __restrict__ wbf, const float* __restrict__ ob,
              const float* __restrict__ lnw, const float* __restrict__ lnb,
              float* __restrict__ hl, int last, int layer) {
    int b = blockIdx.x;
    int chunk = blockIdx.y;            // 8 chunks of 256 l
    int t = threadIdx.x;
    int wave = t >> 6, lane = t & 63;
    int lm = lane & 15, kg = lane >> 4;
    int hch = t & 255, lp = t >> 8;

    __shared__ __align__(16) ushort ys[LT][NH + 8];    // 16.9 KB  [l][h]
    __shared__ __align__(16) ushort resT[NH][40];      // 20.5 KB  [h][l] (pad 40: 16B-aligned rows)
    __shared__ __align__(16) ushort glu[LT][NH + 8];   // 16.9 KB  bf16 pre-LN
    __shared__ float ps[LT][9], pq[LT][9];             // 2.3 KB
    __shared__ float mean_s[LT], rstd_s[LT];

    const ushort* wp = wbf + (size_t)layer * 512 * NH;

    short8 av[4][8];
#pragma unroll
    for (int mi = 0; mi < 4; mi++) {
        int o = (mi < 2 ? wave * 32 + mi * 16 : 256 + wave * 32 + (mi - 2) * 16) + lm;
#pragma unroll
        for (int ks = 0; ks < 8; ks++)
            av[mi][ks] = *(const short8*)(wp + (size_t)o * NH + ks * 32 + kg * 8);
    }

    float oba[2][4], obg[2][4];
#pragma unroll
    for (int mi = 0; mi < 2; mi++)
#pragma unroll
        for (int j = 0; j < 4; j++) {
            int o = wave * 32 + mi * 16 + kg * 4 + j;
            oba[mi][j] = ob[layer * 2 * NH + o];
            obg[mi][j] = ob[layer * 2 * NH + NH + o];
        }
    float lw = lnw[layer * NH + hch], lb = lnb[layer * NH + hch];

    short8 pre0, pre1, rpre0, rpre1;
    {
        int l0 = chunk * 256;
        int c = l0 >> 6, j0 = l0 & 63;
        size_t base = ((size_t)hch * NBC + b * NCH + c) * 64 + j0 + lp * 16;
        pre0 = *(const short8*)(u_t + base);
        pre1 = *(const short8*)(u_t + base + 8);
        rpre0 = *(const short8*)(r_t + base);
        rpre1 = *(const short8*)(r_t + base + 8);
    }

    for (int tile = 0; tile < 8; tile++) {
        int l0 = chunk * 256 + tile * LT;
        int c = l0 >> 6, j0 = l0 & 63;
        size_t tbase = ((size_t)hch * NBC + b * NCH + c) * 64 + j0 + lp * 16;

        // stage ys (transposed, scalar) + res (natural layout, 2 vector writes)
        {
            int li0 = lp * 16;
#pragma unroll
            for (int i = 0; i < 8; i++) ys[li0 + i][hch] = (ushort)pre0[i];
#pragma unroll
            for (int i = 0; i < 8; i++) ys[li0 + 8 + i][hch] = (ushort)pre1[i];
            *(short8*)&resT[hch][li0] = rpre0;
            *(short8*)&resT[hch][li0 + 8] = rpre1;
        }
        if (tile < 7) {
            int l0n = l0 + LT;
            int cn = l0n >> 6, j0n = l0n & 63;
            size_t nbase = ((size_t)hch * NBC + b * NCH + cn) * 64 + j0n + lp * 16;
            pre0 = *(const short8*)(u_t + nbase);
            pre1 = *(const short8*)(u_t + nbase + 8);
            rpre0 = *(const short8*)(r_t + nbase);
            rpre1 = *(const short8*)(r_t + nbase + 8);
        }
        __syncthreads();   // B1: ys/res staged (orders vs prior tile's norm reads of glu/mean)

        f32x4 acc[4][2];
#pragma unroll
        for (int i = 0; i < 4; i++)
#pragma unroll
            for (int j = 0; j < 2; j++) acc[i][j] = (f32x4){0.f, 0.f, 0.f, 0.f};

#pragma unroll
        for (int ks = 0; ks < 8; ks++) {
            short8 bv[2];
#pragma unroll
            for (int ni = 0; ni < 2; ni++)
                bv[ni] = *(const short8*)&ys[ni * 16 + lm][ks * 32 + kg * 8];
#pragma unroll
            for (int mi = 0; mi < 4; mi++)
#pragma unroll
                for (int ni = 0; ni < 2; ni++)
                    acc[mi][ni] = __builtin_amdgcn_mfma_f32_16x16x32_bf16(av[mi][ks], bv[ni], acc[mi][ni], 0, 0, 0);
        }

        // GLU + bias + residual -> glu (bf16); LN partials via kg-shuffle
#pragma unroll
        for (int ni = 0; ni < 2; ni++) {
            int l = ni * 16 + lm;
            float s = 0.f, q = 0.f;
#pragma unroll
            for (int mi = 0; mi < 2; mi++) {
                int o = wave * 32 + mi * 16 + kg * 4;
#pragma unroll
                for (int j = 0; j < 4; j++) {
                    float a = acc[mi][ni][j] + oba[mi][j];
                    float g = acc[mi + 2][ni][j] + obg[mi][j];
                    float v = a * (1.0f / (1.0f + expf(-g))) + bf2f(resT[o + j][l]);
                    glu[l][o + j] = f2bf(v);
                    s += v; q = fmaf(v, v, q);
                }
            }
            s += __shfl_xor(s, 16, 64); q += __shfl_xor(q, 16, 64);
            s += __shfl_xor(s, 32, 64); q += __shfl_xor(q, 32, 64);
            if (kg == 0) { ps[l][wave] = s; pq[l][wave] = q; }
        }
        __syncthreads();   // B2: glu + partials ready

        if (t < LT) {
            float S = 0.f, Q = 0.f;
#pragma unroll
            for (int w = 0; w < 8; w++) { S += ps[t][w]; Q += pq[t][w]; }
            float m = S * (1.0f / NH);
            float v = Q * (1.0f / NH) - m * m;
            mean_s[t] = m; rstd_s[t] = rsqrtf(v + LN_EPS);
        }
        __syncthreads();   // B3: mean/rstd ready

        short8 o0, o1;
#pragma unroll
        for (int lq = 0; lq < 8; lq++) {
            int l = lp * 16 + lq;
            float v = (bf2f(glu[l][hch]) - mean_s[l]) * rstd_s[l] * lw + lb;
            o0[lq] = (short)f2bf(v);
        }
#pragma unroll
        for (int lq = 0; lq < 8; lq++) {
            int l = lp * 16 + 8 + lq;
            float v = (bf2f(glu[l][hch]) - mean_s[l]) * rstd_s[l] * lw + lb;
            o1[lq] = (short)f2bf(v);
            if (last && chunk == 7 && tile == 7 && lp == 1 && lq == 7)
                hl[(size_t)b * NH + hch] = v;   // l = 2047
        }
        ushort* rd = r_t + tbase;
        *(short8*)rd = o0;
        *(short8*)(rd + 8) = o1;
        // no loop barrier: next tile's B1 orders glu/mean rewrites vs these reads
    }
}

// ---------------- head MLP: one wave per output element ----------------
__global__ void __launch_bounds__(256, 4)
s4w_mlp_wave(const float* __restrict__ in, size_t in_bstride,
             const float* __restrict__ w, const float* __restrict__ bias,
             float* __restrict__ out, int K, int N, int do_relu) {
    int wid = (blockIdx.x * 256 + threadIdx.x) >> 6;
    int lane = threadIdx.x & 63;
    if (wid >= NB * N) return;
    int b = wid / N, o = wid % N;
    const float* ip = in + (size_t)b * in_bstride;
    const float* wp = w + (size_t)o * K;
    float acc = 0.f;
    for (int k = lane; k < K; k += 64) acc = fmaf(wp[k], ip[k], acc);
#pragma unroll
    for (int off = 32; off > 0; off >>= 1) acc += __shfl_xor(acc, off, 64);
    if (lane == 0) {
        float v = acc + bias[o];
        out[(size_t)b * N + o] = do_relu ? fmaxf(v, 0.f) : v;
    }
}

extern "C" void kernel_launch(void* const* d_in, const int* in_sizes, int n_in,
                              void* d_out, int out_size, void* d_ws, size_t ws_size,
                              hipStream_t stream) {
    const float* x          = (const float*)d_in[0];
    const float* enc_w      = (const float*)d_in[1];
    const float* enc_b      = (const float*)d_in[2];
    const float* log_dt     = (const float*)d_in[3];
    const float* C_re       = (const float*)d_in[4];
    const float* C_im       = (const float*)d_in[5];
    const float* log_A_real = (const float*)d_in[6];
    const float* A_imag     = (const float*)d_in[7];
    const float* Dp         = (const float*)d_in[8];
    const float* out_w      = (const float*)d_in[9];
    const float* out_b      = (const float*)d_in[10];
    const float* ln_w       = (const float*)d_in[11];
    const float* ln_b       = (const float*)d_in[12];
    const float* lin1_w     = (const float*)d_in[13];
    const float* lin1_b     = (const float*)d_in[14];
    const float* lin2_w     = (const float*)d_in[15];
    const float* lin2_b     = (const float*)d_in[16];
    const float* lin3_w     = (const float*)d_in[17];
    const float* lin3_b     = (const float*)d_in[18];
    float* outp = (float*)d_out;

    float* ws = (float*)d_ws;
    size_t off = 0;
    ushort* r_t = (ushort*)(ws + off);   off += (size_t)NB * LSEQ * NH / 2;
    ushort* u_t = (ushort*)(ws + off);   off += (size_t)NB * LSEQ * NH / 2;
    ushort* wbf = (ushort*)(ws + off);   off += (size_t)NLAY * 2 * NH * NH / 2;
    ushort* wenc = (ushort*)(ws + off);  off += (size_t)NH * DIN / 2;
    ushort* Lmat = (ushort*)(ws + off);  off += (size_t)NLAY * NH * 4096 / 2;
    ushort* Wc   = (ushort*)(ws + off);  off += (size_t)NLAY * NH * 4096 / 2;
    ushort* Vmat = (ushort*)(ws + off);  off += (size_t)NLAY * NH * 4096 / 2;
    float* pr_ = ws + off;               off += NLAY * NH * NN;
    float* pi_ = ws + off;               off += NLAY * NH * NN;
    float* hl  = ws + off;               off += NB * NH;
    float* t1  = ws + off;               off += NB * ML1;
    float* t2  = ws + off;               off += NB * ML2;

    s4w_matprep<<<NLAY * NH, 64, 0, stream>>>(
        log_dt, C_re, C_im, log_A_real, A_imag, Lmat, Wc, Vmat, pr_, pi_);
    s4w_wprep<<<(NLAY * 2 * NH * NH + 255) / 256, 256, 0, stream>>>(out_w, wbf, NLAY * 2 * NH * NH);
    s4w_wprep<<<(NH * DIN + 255) / 256, 256, 0, stream>>>(enc_w, wenc, NH * DIN);

    s4w_enc<<<dim3(NB, 32), 256, 0, stream>>>(x, wenc, enc_b, r_t);

    for (int layer = 0; layer < NLAY; layer++) {
        s4w_conv<<<dim3(NH, NB / 8), 256, 0, stream>>>(r_t, u_t, Lmat, Wc, Vmat, pr_, pi_, Dp, layer);
        s4w_proj_mfma<<<dim3(NB, 8), 512, 0, stream>>>(
            u_t, r_t, wbf, out_b, ln_w, ln_b, hl, layer == NLAY - 1 ? 1 : 0, layer);
    }

    s4w_mlp_wave<<<(NB * ML1 + 3) / 4, 256, 0, stream>>>(
        hl, NH, lin1_w, lin1_b, t1, NH, ML1, 1);
    s4w_mlp_wave<<<(NB * ML2 + 3) / 4, 256, 0, stream>>>(
        t1, ML1, lin2_w, lin2_b, t2, ML1, ML2, 1);
    s4w_mlp_wave<<<(NB * MOUT + 3) / 4, 256, 0, stream>>>(
        t2, ML2, lin3_w, lin3_b, outp, ML2, MOUT, 0);
}